// Round 4
// baseline (716.739 us; speedup 1.0000x reference)
//
#include <hip/hip_runtime.h>

// Fused dequant-gather embedding:
//   out[t, d] = (float)qweight[x[t], d] * scales[x[t], d/128]
// T = 32*2048 = 65536 tokens, D = 1024, G = 8 (group size 128).
//
// R4: 32 B per thread per trip (two int4 loads + two NT float4 stores).
// Halves VMEM instruction count / address math per byte vs R3. Wave reads
// 2 KB contiguous of a single (wave-uniform) row. Tests whether any part of
// the kernel is issue-limited; if neutral again, kernel is at the gather BW
// floor (~80-150 us) and dur_us is dominated by fixed harness fills/restores.

#define NGROUPS 8

typedef float f32x4 __attribute__((ext_vector_type(4)));
typedef int   i32x4 __attribute__((ext_vector_type(4)));

__global__ __launch_bounds__(256) void quant_embed_gather_kernel(
    const int*   __restrict__ x,       // [T] token row indices (int32)
    const int*   __restrict__ qw,      // [VOCAB, DIM] int4 codes as int32
    const float* __restrict__ sc,      // [VOCAB, NGROUPS]
    float*       __restrict__ out,     // [T, DIM]
    int total_units)                   // T * 128 (one unit = 8 elements = 32 B)
{
    const int tid    = blockIdx.x * blockDim.x + threadIdx.x;
    const int stride = gridDim.x * blockDim.x;   // 524288 -> 16 trips/thread

    #pragma unroll 2
    for (int u = tid; u < total_units; u += stride) {
        const int token = u >> 7;       // unit / 128
        const int w8    = u & 127;      // unit within the row
        const int row   = x[token];     // wave-uniform broadcast load

        // 8 consecutive elements starting at d0 = w8*8; group = d0/128 = w8/16
        const float s = sc[row * NGROUPS + (w8 >> 4)];

        const long long qbase = ((long long)row << 10) + (w8 << 3);
        const i32x4 q0 = *reinterpret_cast<const i32x4*>(qw + qbase);
        const i32x4 q1 = *reinterpret_cast<const i32x4*>(qw + qbase + 4);

        f32x4 o0, o1;
        o0.x = (float)q0.x * s;  o0.y = (float)q0.y * s;
        o0.z = (float)q0.z * s;  o0.w = (float)q0.w * s;
        o1.x = (float)q1.x * s;  o1.y = (float)q1.y * s;
        o1.z = (float)q1.z * s;  o1.w = (float)q1.w * s;

        float* dst = out + ((long long)u << 3);
        __builtin_nontemporal_store(o0, reinterpret_cast<f32x4*>(dst));
        __builtin_nontemporal_store(o1, reinterpret_cast<f32x4*>(dst + 4));
    }
}

extern "C" void kernel_launch(void* const* d_in, const int* in_sizes, int n_in,
                              void* d_out, int out_size, void* d_ws, size_t ws_size,
                              hipStream_t stream) {
    const int*   x  = (const int*)d_in[0];     // [65536]
    const int*   qw = (const int*)d_in[1];     // [128000*1024]
    const float* sc = (const float*)d_in[2];   // [128000*8]
    float* out = (float*)d_out;                // [65536*1024]

    const int total_units = out_size / 8;      // 8,388,608
    const int block = 256;
    const int grid  = 2048;                    // 8192 waves: full 256-CU occupancy

    quant_embed_gather_kernel<<<grid, block, 0, stream>>>(x, qw, sc, out, total_units);
}